// Round 6
// baseline (3637.666 us; speedup 1.0000x reference)
//
#include <hip/hip_runtime.h>
#include <math.h>

// Problem constants
#define RR 16384        // B*N rows
#define DD 512          // feature dim
#define CC 4096         // codebook size
#define QQ 4            // num quantizers
#define NB 32           // codebook n-chunks (CC/128)
#define QOUT_SZ (RR*DD)
#define IDX_OFF QOUT_SZ
#define LOSS_OFF (QOUT_SZ + RR*QQ)
#define LOSS_COEF (1.25f / 8388608.0f)

// Workspace layout (float offsets)
#define WS_RESID 0
#define WS_CBN   (RR*DD)                    // 8388608
#define WS_RNRM  (WS_CBN + CC*DD)           // 10485760
#define WS_PV    (WS_RNRM + RR)             // 10502144  (RR*NB*4)
#define WS_PI    (WS_PV + RR*NB*4)          // 12599296
#define WS_LOSS  (WS_PI + RR*NB*4)          // 14696448
#define WS_F16   (WS_LOSS + 4)              // 14696452 (byte offset *4 -> 16B aligned)
// f16 region (offsets in halves from WS_F16 base)
#define F16_A 0
#define F16_B (RR*DD)

typedef _Float16 f16x8 __attribute__((ext_vector_type(8)));
typedef float f32x4 __attribute__((ext_vector_type(4)));

__device__ __forceinline__ float waveSum(float v) {
#pragma unroll
    for (int m = 1; m < 64; m <<= 1) v += __shfl_xor(v, m, 64);
    return v;
}

// insert (v,c) into sorted top-4 (desc value, ties -> smaller index first)
__device__ __forceinline__ void top4add(float v, int c, float* V, int* I) {
    if (v > V[0] || (v == V[0] && c < I[0])) {
        V[3]=V[2]; I[3]=I[2]; V[2]=V[1]; I[2]=I[1]; V[1]=V[0]; I[1]=I[0]; V[0]=v; I[0]=c;
    } else if (v > V[1] || (v == V[1] && c < I[1])) {
        V[3]=V[2]; I[3]=I[2]; V[2]=V[1]; I[2]=I[1]; V[1]=v; I[1]=c;
    } else if (v > V[2] || (v == V[2] && c < I[2])) {
        V[3]=V[2]; I[3]=I[2]; V[2]=v; I[2]=c;
    } else if (v > V[3] || (v == V[3] && c < I[3])) {
        V[3]=v; I[3]=c;
    }
}

// ---------------- init: resid = x, qout = 0, loss = 0 ----------------
__global__ void initK(const float* __restrict__ x, float* __restrict__ resid,
                      float* __restrict__ dout, float* __restrict__ loss) {
    int i = blockIdx.x * blockDim.x + threadIdx.x;
    int stride = gridDim.x * blockDim.x;
    for (; i < QOUT_SZ; i += stride) { resid[i] = x[i]; dout[i] = 0.0f; }
    if (blockIdx.x == 0 && threadIdx.x < QQ) loss[threadIdx.x] = 0.0f;
}

// ---------------- implicit_cb = codebooks[q] @ weights[q]^T ----------------
__global__ __launch_bounds__(256) void gemmCbK(const float* __restrict__ A,
                                               const float* __restrict__ W,
                                               float* __restrict__ out) {
    __shared__ float As[32][64];
    __shared__ float Bs[32][64];
    int t = threadIdx.x;
    int tx = t & 15, ty = t >> 4;
    int cBase = blockIdx.x * 64;
    int dBase = blockIdx.y * 64;
    int f = t & 7;
    int mq = t >> 3;
    float acc[4][4] = {};
    for (int k0 = 0; k0 < DD; k0 += 32) {
        __syncthreads();
#pragma unroll
        for (int p = 0; p < 2; ++p) {
            int m = mq + p * 32;
            float4 av = *(const float4*)&A[(size_t)(cBase + m) * DD + k0 + f * 4];
            As[f*4+0][m] = av.x; As[f*4+1][m] = av.y; As[f*4+2][m] = av.z; As[f*4+3][m] = av.w;
            float4 wv = *(const float4*)&W[(size_t)(dBase + m) * DD + k0 + f * 4];
            Bs[f*4+0][m] = wv.x; Bs[f*4+1][m] = wv.y; Bs[f*4+2][m] = wv.z; Bs[f*4+3][m] = wv.w;
        }
        __syncthreads();
#pragma unroll
        for (int kk = 0; kk < 32; ++kk) {
            float4 a4 = *(const float4*)&As[kk][ty * 4];
            float4 b4 = *(const float4*)&Bs[kk][tx * 4];
            float a[4] = {a4.x, a4.y, a4.z, a4.w};
            float b[4] = {b4.x, b4.y, b4.z, b4.w};
#pragma unroll
            for (int i = 0; i < 4; ++i)
#pragma unroll
                for (int j = 0; j < 4; ++j) acc[i][j] += a[i] * b[j];
        }
    }
#pragma unroll
    for (int i = 0; i < 4; ++i) {
        float4 v = make_float4(acc[i][0], acc[i][1], acc[i][2], acc[i][3]);
        *(float4*)&out[(size_t)(cBase + ty * 4 + i) * DD + dBase + tx * 4] = v;
    }
}

// ------- normalize cbn rows in place + emit f16 copy (one wave/row) ----------
__global__ void rowNormCvtK(float* __restrict__ buf, _Float16* __restrict__ bf16) {
    int wave = threadIdx.x >> 6, lane = threadIdx.x & 63;
    int row = blockIdx.x * 4 + wave;
    float* p = buf + (size_t)row * DD;
    float4 v0 = *(float4*)&p[lane * 8];
    float4 v1 = *(float4*)&p[lane * 8 + 4];
    float ss = v0.x*v0.x + v0.y*v0.y + v0.z*v0.z + v0.w*v0.w
             + v1.x*v1.x + v1.y*v1.y + v1.z*v1.z + v1.w*v1.w;
    ss = waveSum(ss);
    float nrm = fmaxf(sqrtf(ss), 1e-12f);
    float vals[8] = {v0.x/nrm, v0.y/nrm, v0.z/nrm, v0.w/nrm,
                     v1.x/nrm, v1.y/nrm, v1.z/nrm, v1.w/nrm};
    *(float4*)&p[lane * 8]     = make_float4(vals[0], vals[1], vals[2], vals[3]);
    *(float4*)&p[lane * 8 + 4] = make_float4(vals[4], vals[5], vals[6], vals[7]);
    f16x8 hv;
#pragma unroll
    for (int j = 0; j < 8; ++j) hv[j] = (_Float16)vals[j];
    *(f16x8*)&bf16[(size_t)row * DD + lane * 8] = hv;
}

// ------- resid row norms + f16 copy of RAW resid (q=0 only) ------------------
__global__ void residCvtK(const float* __restrict__ resid,
                          float* __restrict__ rnrm, _Float16* __restrict__ af16) {
    int wave = threadIdx.x >> 6, lane = threadIdx.x & 63;
    int row = blockIdx.x * 4 + wave;
    const float* p = resid + (size_t)row * DD;
    float4 v0 = *(const float4*)&p[lane * 8];
    float4 v1 = *(const float4*)&p[lane * 8 + 4];
    float vals[8] = {v0.x, v0.y, v0.z, v0.w, v1.x, v1.y, v1.z, v1.w};
    float ss = 0.f;
#pragma unroll
    for (int j = 0; j < 8; ++j) ss += vals[j] * vals[j];
    ss = waveSum(ss);
    if (lane == 0) rnrm[row] = fmaxf(sqrtf(ss), 1e-12f);
    f16x8 hv;
#pragma unroll
    for (int j = 0; j < 8; ++j) hv[j] = (_Float16)vals[j];
    *(f16x8*)&af16[(size_t)row * DD + lane * 8] = hv;
}

// ---------------- single-pass f16 MFMA sim GEMM + fused top-4 ----------------
// 128x128 tile, BK=64 (halves), 256 thr / 4 waves, 16x16x32 f16 MFMA.
// Register-budget engineering (R5 post-mortem): demand ~145 regs (64 acc +
// 32 af + 8 bf + addressing). The scheduler targets LDS-capped occupancy and
// WILL spill to reach it; with LDS at exactly 40 KB that target was 4 waves/EU
// (128-reg budget) -> ~60 spilled regs -> 1.95 GB/dispatch scratch writes.
// Therefore: (a) amdgpu_waves_per_eu(1,3) caps the target at 3 waves/EU
// (~170-reg budget); (b) LDS padded past 40 KB so the LDS cap itself is
// 3 blocks/CU even if (a) is ignored; (c) bf loaded one tile at a time.
__global__ __launch_bounds__(256)
__attribute__((amdgpu_waves_per_eu(1, 3)))
void simMfmaK(
    const _Float16* __restrict__ Af16, const _Float16* __restrict__ Bf16,
    float* __restrict__ pv, int* __restrict__ pi) {
    __shared__ _Float16 Alds[128 * 64];
    __shared__ _Float16 Blds[128 * 64];
    __shared__ float sV[2][128][4];
    __shared__ int   sI[2][128][4];
    __shared__ float ldsPad[300];   // push LDS past 40 KB -> 3 blocks/CU cap
    int t = threadIdx.x, w = t >> 6, lane = t & 63;
    if ((size_t)pv == 1) ((volatile float*)ldsPad)[t] = 1.f;  // keep pad alive
    int rowBase = blockIdx.x * 128;
    int cBase = blockIdx.y * 128;
    int mbase = (w & 1) * 64, nbase = (w >> 1) * 64;
    int l15 = lane & 15, quad = lane >> 4;

    f32x4 acc[4][4];
#pragma unroll
    for (int i = 0; i < 4; ++i)
#pragma unroll
        for (int j = 0; j < 4; ++j) acc[i][j] = (f32x4){0.f, 0.f, 0.f, 0.f};

    // staging geometry: lane covers 16 B; 8 lanes per 128-B row; source chunk
    // XOR-swizzled so LDS row r physically holds chunk c at slot c^(r&7).
    int rsub = lane >> 3;                 // 0..7 row within 8-row group
    int swz = (lane & 7) ^ rsub;          // source 16B-chunk index

    for (int k0 = 0; k0 < DD; k0 += 64) {
        __syncthreads();
#pragma unroll
        for (int j = 0; j < 4; ++j) {
            int rA = rowBase + 32 * w + 8 * j + rsub;
            int rB = cBase + 32 * w + 8 * j + rsub;
            __builtin_amdgcn_global_load_lds(
                (const __attribute__((address_space(1))) void*)&Af16[(size_t)rA * DD + k0 + swz * 8],
                (__attribute__((address_space(3))) void*)&Alds[(32 * w + 8 * j) * 64], 16, 0, 0);
            __builtin_amdgcn_global_load_lds(
                (const __attribute__((address_space(1))) void*)&Bf16[(size_t)rB * DD + k0 + swz * 8],
                (__attribute__((address_space(3))) void*)&Blds[(32 * w + 8 * j) * 64], 16, 0, 0);
        }
        __syncthreads();
#pragma unroll
        for (int kh = 0; kh < 2; ++kh) {
            int chunk = (kh * 4 + quad) ^ (l15 & 7);   // row&7 == l15&7 for all tiles
            f16x8 af[4];
#pragma unroll
            for (int tm = 0; tm < 4; ++tm)
                af[tm] = *(const f16x8*)&Alds[(mbase + tm * 16 + l15) * 64 + chunk * 8];
#pragma unroll
            for (int tn = 0; tn < 4; ++tn) {
                f16x8 bf = *(const f16x8*)&Blds[(nbase + tn * 16 + l15) * 64 + chunk * 8];
#pragma unroll
                for (int tm = 0; tm < 4; ++tm)
                    acc[tm][tn] = __builtin_amdgcn_mfma_f32_16x16x32_f16(
                        af[tm], bf, acc[tm][tn], 0, 0, 0);
            }
        }
    }

    // epilogue: per-row top-4 over this block's 128 columns
    // D layout: lane,reg r -> row = quad*4+r (in 16-tile), col = l15
#pragma unroll
    for (int tm = 0; tm < 4; ++tm) {
#pragma unroll
        for (int r = 0; r < 4; ++r) {
            float V[4] = {-3e38f, -3e38f, -3e38f, -3e38f};
            int   I[4] = {0x7fffffff, 0x7fffffff, 0x7fffffff, 0x7fffffff};
#pragma unroll
            for (int tn = 0; tn < 4; ++tn)
                top4add(acc[tm][tn][r], cBase + nbase + tn * 16 + l15, V, I);
#pragma unroll
            for (int m = 1; m < 16; m <<= 1) {
#pragma unroll
                for (int j = 0; j < 4; ++j) {
                    float ov = __shfl_xor(V[j], m, 64);
                    int oc = __shfl_xor(I[j], m, 64);
                    top4add(ov, oc, V, I);
                }
            }
            if (l15 == 0) {
                int rowl = mbase + tm * 16 + quad * 4 + r;
                int slot = w >> 1;
#pragma unroll
                for (int j = 0; j < 4; ++j) { sV[slot][rowl][j] = V[j]; sI[slot][rowl][j] = I[j]; }
            }
        }
    }
    __syncthreads();
    if (t < 128) {
        float V[4]; int I[4];
#pragma unroll
        for (int j = 0; j < 4; ++j) { V[j] = sV[0][t][j]; I[j] = sI[0][t][j]; }
#pragma unroll
        for (int j = 0; j < 4; ++j) top4add(sV[1][t][j], sI[1][t][j], V, I);
        size_t o = ((size_t)(rowBase + t) * NB + blockIdx.y) * 4;
#pragma unroll
        for (int j = 0; j < 4; ++j) { pv[o + j] = V[j]; pi[o + j] = I[j]; }
    }
}

// -------- finalize: merge chunk top-4s, fp32 rescore, rotation, updates,
//          and emit next-q residual f16 + rnrm (fused residCvt) --------------
__global__ void finalizeK(float* __restrict__ resid,
                          float* __restrict__ rnrm,
                          const float* __restrict__ cbn,
                          const float* __restrict__ pv, const int* __restrict__ pi,
                          float* __restrict__ dout,
                          float* __restrict__ loss,
                          _Float16* __restrict__ af16, int q) {
    int wave = threadIdx.x >> 6, lane = threadIdx.x & 63;
    int row = blockIdx.x * 4 + wave;
    float* xr = resid + (size_t)row * DD;
    float nrm = rnrm[row];
    float4 a0 = *(float4*)&xr[lane * 8];
    float4 a1 = *(float4*)&xr[lane * 8 + 4];
    float orig[8] = {a0.x,a0.y,a0.z,a0.w,a1.x,a1.y,a1.z,a1.w};
    float x[8];
#pragma unroll
    for (int j = 0; j < 8; ++j) x[j] = orig[j] / nrm;   // x_n per reference

    // merge 32 chunk top-4 partials (lane i < 32 loads chunk i)
    float V[4] = {-3e38f, -3e38f, -3e38f, -3e38f};
    int   I[4] = {0x7fffffff, 0x7fffffff, 0x7fffffff, 0x7fffffff};
    if (lane < NB) {
        size_t o = ((size_t)row * NB + lane) * 4;
#pragma unroll
        for (int j = 0; j < 4; ++j) { V[j] = pv[o + j]; I[j] = pi[o + j]; }
    }
#pragma unroll
    for (int m = 1; m < 32; m <<= 1) {
#pragma unroll
        for (int j = 0; j < 4; ++j) {
            float ov = __shfl_xor(V[j], m, 64);
            int oc = __shfl_xor(I[j], m, 64);
            top4add(ov, oc, V, I);
        }
    }
    int cand[4];
#pragma unroll
    for (int j = 0; j < 4; ++j) cand[j] = __shfl(I[j], 0, 64);

    // exact fp32 rescore of the 4 nominated candidates on the normalized row
    float sBest = -3e38f; int idx = 0x7fffffff;
#pragma unroll
    for (int j = 0; j < 4; ++j) {
        const float* cbj = cbn + (size_t)cand[j] * DD;
        float s = 0.f;
#pragma unroll
        for (int e = 0; e < 8; ++e) s += x[e] * cbj[lane * 8 + e];
        s = waveSum(s);
        if (s > sBest || (s == sBest && cand[j] < idx)) { sBest = s; idx = cand[j]; }
    }

    const float* qp = cbn + (size_t)idx * DD;
    float4 q0 = *(const float4*)&qp[lane * 8];
    float4 q1 = *(const float4*)&qp[lane * 8 + 4];
    float qv[8] = {q0.x,q0.y,q0.z,q0.w,q1.x,q1.y,q1.z,q1.w};

    float ns2 = 0.f, nt2 = 0.f, lrow = 0.f;
#pragma unroll
    for (int j = 0; j < 8; ++j) {
        ns2 += x[j] * x[j];
        nt2 += qv[j] * qv[j];
        float d = x[j] - qv[j];
        lrow += d * d;
    }
    ns2 = waveSum(ns2); nt2 = waveSum(nt2); lrow = waveSum(lrow);
    float ns = sqrtf(ns2), nt = sqrtf(nt2);

    float u[8], qn[8], wv[8];
    float nw2 = 0.f;
#pragma unroll
    for (int j = 0; j < 8; ++j) {
        u[j] = x[j] / ns;
        qn[j] = qv[j] / nt;
        wv[j] = u[j] + qn[j];
        nw2 += wv[j] * wv[j];
    }
    nw2 = waveSum(nw2);
    float nw = fmaxf(sqrtf(nw2), 1e-12f);
    float dew = 0.f, deu = 0.f;
#pragma unroll
    for (int j = 0; j < 8; ++j) {
        wv[j] = wv[j] / nw;
        dew += x[j] * wv[j];
        deu += x[j] * u[j];
    }
    dew = waveSum(dew); deu = waveSum(deu);
    float scale = nt / ns;

    float r[8], nres[8];
    float ss = 0.f;
#pragma unroll
    for (int j = 0; j < 8; ++j) {
        r[j] = (x[j] - 2.0f * dew * wv[j] + 2.0f * deu * qn[j]) * scale;
        nres[j] = orig[j] - r[j];
        ss += nres[j] * nres[j];
    }

    // residual -= r ; emit f16 residual + next rnrm (fused residCvt)
    *(float4*)&xr[lane * 8]     = make_float4(nres[0], nres[1], nres[2], nres[3]);
    *(float4*)&xr[lane * 8 + 4] = make_float4(nres[4], nres[5], nres[6], nres[7]);
    ss = waveSum(ss);
    if (lane == 0) rnrm[row] = fmaxf(sqrtf(ss), 1e-12f);
    f16x8 hv;
#pragma unroll
    for (int j = 0; j < 8; ++j) hv[j] = (_Float16)nres[j];
    *(f16x8*)&af16[(size_t)row * DD + lane * 8] = hv;

    float* op = dout + (size_t)row * DD;
    float4 o0 = *(float4*)&op[lane * 8];
    float4 o1 = *(float4*)&op[lane * 8 + 4];
    o0.x += r[0]; o0.y += r[1]; o0.z += r[2]; o0.w += r[3];
    o1.x += r[4]; o1.y += r[5]; o1.z += r[6]; o1.w += r[7];
    *(float4*)&op[lane * 8] = o0;
    *(float4*)&op[lane * 8 + 4] = o1;

    if (lane == 0) {
        dout[IDX_OFF + row * 4 + q] = (float)idx;
        atomicAdd(loss + q, lrow * LOSS_COEF);
    }
}

__global__ void lossWriteK(const float* __restrict__ loss, float* __restrict__ dout) {
    if (threadIdx.x < QQ) dout[LOSS_OFF + threadIdx.x] = loss[threadIdx.x];
}

extern "C" void kernel_launch(void* const* d_in, const int* in_sizes, int n_in,
                              void* d_out, int out_size, void* d_ws, size_t ws_size,
                              hipStream_t stream) {
    const float* x = (const float*)d_in[0];
    const float* codebooks = (const float*)d_in[1];
    const float* weights = (const float*)d_in[2];
    float* dout = (float*)d_out;
    float* w = (float*)d_ws;

    float* resid = w + WS_RESID;
    float* cbn   = w + WS_CBN;
    float* rnrm  = w + WS_RNRM;
    float* pv    = w + WS_PV;
    int*   pi    = (int*)(w + WS_PI);
    float* loss  = w + WS_LOSS;
    _Float16* f16base = (_Float16*)(w + WS_F16);
    _Float16* Af16 = f16base + F16_A;
    _Float16* Bf16 = f16base + F16_B;

    initK<<<4096, 256, 0, stream>>>(x, resid, dout, loss);
    residCvtK<<<RR / 4, 256, 0, stream>>>(resid, rnrm, Af16);

    for (int q = 0; q < QQ; ++q) {
        gemmCbK<<<dim3(CC / 64, DD / 64), 256, 0, stream>>>(
            codebooks + (size_t)q * CC * DD, weights + (size_t)q * DD * DD, cbn);
        rowNormCvtK<<<CC / 4, 256, 0, stream>>>(cbn, Bf16);
        simMfmaK<<<dim3(RR / 128, NB), 256, 0, stream>>>(Af16, Bf16, pv, pi);
        finalizeK<<<RR / 4, 256, 0, stream>>>(resid, rnrm, cbn, pv, pi,
                                              dout, loss, Af16, q);
    }
    lossWriteK<<<1, 64, 0, stream>>>(loss, dout);
}

// Round 7
// 2396.125 us; speedup vs baseline: 1.5181x; 1.5181x over previous
//
#include <hip/hip_runtime.h>
#include <math.h>

// Problem constants
#define RR 16384        // B*N rows
#define DD 512          // feature dim
#define CC 4096         // codebook size
#define QQ 4            // num quantizers
#define NB 32           // codebook n-chunks (CC/128)
#define QOUT_SZ (RR*DD)
#define IDX_OFF QOUT_SZ
#define LOSS_OFF (QOUT_SZ + RR*QQ)
#define LOSS_COEF (1.25f / 8388608.0f)

// Workspace layout (float offsets)
#define WS_RESID 0
#define WS_CBN   (RR*DD)                    // 8388608
#define WS_RNRM  (WS_CBN + CC*DD)           // 10485760
#define WS_PV    (WS_RNRM + RR)             // 10502144  (RR*NB*4)
#define WS_PI    (WS_PV + RR*NB*4)          // 12599296
#define WS_LOSS  (WS_PI + RR*NB*4)          // 14696448
#define WS_F16   (WS_LOSS + 4)              // 14696452 (byte offset *4 -> 16B aligned)
// f16 region (offsets in halves from WS_F16 base)
#define F16_A 0
#define F16_B (RR*DD)

typedef _Float16 f16x8 __attribute__((ext_vector_type(8)));
typedef float f32x4 __attribute__((ext_vector_type(4)));

__device__ __forceinline__ float waveSum(float v) {
#pragma unroll
    for (int m = 1; m < 64; m <<= 1) v += __shfl_xor(v, m, 64);
    return v;
}

// insert (v,c) into sorted top-4 (desc value, ties -> smaller index first)
__device__ __forceinline__ void top4add(float v, int c, float* V, int* I) {
    if (v > V[0] || (v == V[0] && c < I[0])) {
        V[3]=V[2]; I[3]=I[2]; V[2]=V[1]; I[2]=I[1]; V[1]=V[0]; I[1]=I[0]; V[0]=v; I[0]=c;
    } else if (v > V[1] || (v == V[1] && c < I[1])) {
        V[3]=V[2]; I[3]=I[2]; V[2]=V[1]; I[2]=I[1]; V[1]=v; I[1]=c;
    } else if (v > V[2] || (v == V[2] && c < I[2])) {
        V[3]=V[2]; I[3]=I[2]; V[2]=v; I[2]=c;
    } else if (v > V[3] || (v == V[3] && c < I[3])) {
        V[3]=v; I[3]=c;
    }
}

// ---------------- init: resid = x, qout = 0, loss = 0 ----------------
__global__ void initK(const float* __restrict__ x, float* __restrict__ resid,
                      float* __restrict__ dout, float* __restrict__ loss) {
    int i = blockIdx.x * blockDim.x + threadIdx.x;
    int stride = gridDim.x * blockDim.x;
    for (; i < QOUT_SZ; i += stride) { resid[i] = x[i]; dout[i] = 0.0f; }
    if (blockIdx.x == 0 && threadIdx.x < QQ) loss[threadIdx.x] = 0.0f;
}

// ---------------- implicit_cb = codebooks[q] @ weights[q]^T ----------------
__global__ __launch_bounds__(256) void gemmCbK(const float* __restrict__ A,
                                               const float* __restrict__ W,
                                               float* __restrict__ out) {
    __shared__ float As[32][64];
    __shared__ float Bs[32][64];
    int t = threadIdx.x;
    int tx = t & 15, ty = t >> 4;
    int cBase = blockIdx.x * 64;
    int dBase = blockIdx.y * 64;
    int f = t & 7;
    int mq = t >> 3;
    float acc[4][4] = {};
    for (int k0 = 0; k0 < DD; k0 += 32) {
        __syncthreads();
#pragma unroll
        for (int p = 0; p < 2; ++p) {
            int m = mq + p * 32;
            float4 av = *(const float4*)&A[(size_t)(cBase + m) * DD + k0 + f * 4];
            As[f*4+0][m] = av.x; As[f*4+1][m] = av.y; As[f*4+2][m] = av.z; As[f*4+3][m] = av.w;
            float4 wv = *(const float4*)&W[(size_t)(dBase + m) * DD + k0 + f * 4];
            Bs[f*4+0][m] = wv.x; Bs[f*4+1][m] = wv.y; Bs[f*4+2][m] = wv.z; Bs[f*4+3][m] = wv.w;
        }
        __syncthreads();
#pragma unroll
        for (int kk = 0; kk < 32; ++kk) {
            float4 a4 = *(const float4*)&As[kk][ty * 4];
            float4 b4 = *(const float4*)&Bs[kk][tx * 4];
            float a[4] = {a4.x, a4.y, a4.z, a4.w};
            float b[4] = {b4.x, b4.y, b4.z, b4.w};
#pragma unroll
            for (int i = 0; i < 4; ++i)
#pragma unroll
                for (int j = 0; j < 4; ++j) acc[i][j] += a[i] * b[j];
        }
    }
#pragma unroll
    for (int i = 0; i < 4; ++i) {
        float4 v = make_float4(acc[i][0], acc[i][1], acc[i][2], acc[i][3]);
        *(float4*)&out[(size_t)(cBase + ty * 4 + i) * DD + dBase + tx * 4] = v;
    }
}

// ------- normalize cbn rows in place + emit f16 copy (one wave/row) ----------
__global__ void rowNormCvtK(float* __restrict__ buf, _Float16* __restrict__ bf16) {
    int wave = threadIdx.x >> 6, lane = threadIdx.x & 63;
    int row = blockIdx.x * 4 + wave;
    float* p = buf + (size_t)row * DD;
    float4 v0 = *(float4*)&p[lane * 8];
    float4 v1 = *(float4*)&p[lane * 8 + 4];
    float ss = v0.x*v0.x + v0.y*v0.y + v0.z*v0.z + v0.w*v0.w
             + v1.x*v1.x + v1.y*v1.y + v1.z*v1.z + v1.w*v1.w;
    ss = waveSum(ss);
    float nrm = fmaxf(sqrtf(ss), 1e-12f);
    float vals[8] = {v0.x/nrm, v0.y/nrm, v0.z/nrm, v0.w/nrm,
                     v1.x/nrm, v1.y/nrm, v1.z/nrm, v1.w/nrm};
    *(float4*)&p[lane * 8]     = make_float4(vals[0], vals[1], vals[2], vals[3]);
    *(float4*)&p[lane * 8 + 4] = make_float4(vals[4], vals[5], vals[6], vals[7]);
    f16x8 hv;
#pragma unroll
    for (int j = 0; j < 8; ++j) hv[j] = (_Float16)vals[j];
    *(f16x8*)&bf16[(size_t)row * DD + lane * 8] = hv;
}

// ------- resid row norms + f16 copy of RAW resid (q=0 only) ------------------
__global__ void residCvtK(const float* __restrict__ resid,
                          float* __restrict__ rnrm, _Float16* __restrict__ af16) {
    int wave = threadIdx.x >> 6, lane = threadIdx.x & 63;
    int row = blockIdx.x * 4 + wave;
    const float* p = resid + (size_t)row * DD;
    float4 v0 = *(const float4*)&p[lane * 8];
    float4 v1 = *(const float4*)&p[lane * 8 + 4];
    float vals[8] = {v0.x, v0.y, v0.z, v0.w, v1.x, v1.y, v1.z, v1.w};
    float ss = 0.f;
#pragma unroll
    for (int j = 0; j < 8; ++j) ss += vals[j] * vals[j];
    ss = waveSum(ss);
    if (lane == 0) rnrm[row] = fmaxf(sqrtf(ss), 1e-12f);
    f16x8 hv;
#pragma unroll
    for (int j = 0; j < 8; ++j) hv[j] = (_Float16)vals[j];
    *(f16x8*)&af16[(size_t)row * DD + lane * 8] = hv;
}

// ---------------- single-pass f16 MFMA sim GEMM + fused top-4 ----------------
// 128x128 tile, BK=64, **512 threads / 8 waves**, 16x16x32 f16 MFMA.
// R6 post-mortem: with 4 waves and acc[4][4] (64 f32/lane) the allocator
// produced an 84-VGPR body with ~2 GB/dispatch scratch writes, and neither
// launch_bounds nor amdgpu_waves_per_eu changed it. Fix: halve per-thread
// state. Each of 8 waves owns a 32x64 sub-tile -> acc[2][4] = 32 f32/lane,
// af[2]=8, bf=4 regs: ~70 total, below every plausible budget -> no spill.
__global__ __launch_bounds__(512)
__attribute__((amdgpu_waves_per_eu(1, 4)))
void simMfmaK(
    const _Float16* __restrict__ Af16, const _Float16* __restrict__ Bf16,
    float* __restrict__ pv, int* __restrict__ pi) {
    __shared__ _Float16 Alds[128 * 64];   // 16 KB
    __shared__ _Float16 Blds[128 * 64];   // 16 KB
    __shared__ float sV[2][128][4];       // 4 KB
    __shared__ int   sI[2][128][4];       // 4 KB
    __shared__ float ldsPad[384];         // 1.5 KB -> 41.5 KB total -> 3 blocks/CU
    int t = threadIdx.x, w = t >> 6, lane = t & 63;
    if ((size_t)pv == 1) ((volatile float*)ldsPad)[t & 255] = 1.f;  // keep pad alive
    int rowBase = blockIdx.x * 128;
    int cBase = blockIdx.y * 128;
    int mbase = (w & 3) * 32, nbase = (w >> 2) * 64;
    int l15 = lane & 15, quad = lane >> 4;

    f32x4 acc[2][4];
#pragma unroll
    for (int i = 0; i < 2; ++i)
#pragma unroll
        for (int j = 0; j < 4; ++j) acc[i][j] = (f32x4){0.f, 0.f, 0.f, 0.f};

    // staging: lane covers 16 B; 8 lanes per 128-B row; wave w stages rows
    // 8w..8w+7 (+64 on round 2). Source chunk XOR-swizzled so LDS row r holds
    // chunk c at slot c^(r&7); dest stays contiguous (wave-uniform base).
    int rsub = lane >> 3;                 // 0..7 row within the wave's 8-row group
    int swz = (lane & 7) ^ rsub;          // source 16B-chunk index

    for (int k0 = 0; k0 < DD; k0 += 64) {
        __syncthreads();
#pragma unroll
        for (int j = 0; j < 2; ++j) {
            int rA = rowBase + j * 64 + 8 * w + rsub;
            int rB = cBase + j * 64 + 8 * w + rsub;
            __builtin_amdgcn_global_load_lds(
                (const __attribute__((address_space(1))) void*)&Af16[(size_t)rA * DD + k0 + swz * 8],
                (__attribute__((address_space(3))) void*)&Alds[(j * 64 + 8 * w) * 64], 16, 0, 0);
            __builtin_amdgcn_global_load_lds(
                (const __attribute__((address_space(1))) void*)&Bf16[(size_t)rB * DD + k0 + swz * 8],
                (__attribute__((address_space(3))) void*)&Blds[(j * 64 + 8 * w) * 64], 16, 0, 0);
        }
        __syncthreads();
#pragma unroll
        for (int kh = 0; kh < 2; ++kh) {
            int chunk = (kh * 4 + quad) ^ (l15 & 7);   // row&7 == l15&7 for all tiles
            f16x8 af[2];
#pragma unroll
            for (int tm = 0; tm < 2; ++tm)
                af[tm] = *(const f16x8*)&Alds[(mbase + tm * 16 + l15) * 64 + chunk * 8];
#pragma unroll
            for (int tn = 0; tn < 4; ++tn) {
                f16x8 bf = *(const f16x8*)&Blds[(nbase + tn * 16 + l15) * 64 + chunk * 8];
#pragma unroll
                for (int tm = 0; tm < 2; ++tm)
                    acc[tm][tn] = __builtin_amdgcn_mfma_f32_16x16x32_f16(
                        af[tm], bf, acc[tm][tn], 0, 0, 0);
            }
        }
    }

    // epilogue: per wave, top-4 per row over its 64 columns
    // D layout: lane,reg r -> row = quad*4+r (in 16-tile), col = l15
#pragma unroll
    for (int tm = 0; tm < 2; ++tm) {
#pragma unroll
        for (int r = 0; r < 4; ++r) {
            float V[4] = {-3e38f, -3e38f, -3e38f, -3e38f};
            int   I[4] = {0x7fffffff, 0x7fffffff, 0x7fffffff, 0x7fffffff};
#pragma unroll
            for (int tn = 0; tn < 4; ++tn)
                top4add(acc[tm][tn][r], cBase + nbase + tn * 16 + l15, V, I);
#pragma unroll
            for (int m = 1; m < 16; m <<= 1) {
#pragma unroll
                for (int j = 0; j < 4; ++j) {
                    float ov = __shfl_xor(V[j], m, 64);
                    int oc = __shfl_xor(I[j], m, 64);
                    top4add(ov, oc, V, I);
                }
            }
            if (l15 == 0) {
                int rowl = mbase + tm * 16 + quad * 4 + r;
                int slot = w >> 2;              // which 64-col half
#pragma unroll
                for (int j = 0; j < 4; ++j) { sV[slot][rowl][j] = V[j]; sI[slot][rowl][j] = I[j]; }
            }
        }
    }
    __syncthreads();
    if (t < 128) {
        float V[4]; int I[4];
#pragma unroll
        for (int j = 0; j < 4; ++j) { V[j] = sV[0][t][j]; I[j] = sI[0][t][j]; }
#pragma unroll
        for (int j = 0; j < 4; ++j) top4add(sV[1][t][j], sI[1][t][j], V, I);
        size_t o = ((size_t)(rowBase + t) * NB + blockIdx.y) * 4;
#pragma unroll
        for (int j = 0; j < 4; ++j) { pv[o + j] = V[j]; pi[o + j] = I[j]; }
    }
}

// -------- finalize: merge chunk top-4s, fp32 rescore, rotation, updates,
//          and emit next-q residual f16 + rnrm (fused residCvt) --------------
__global__ void finalizeK(float* __restrict__ resid,
                          float* __restrict__ rnrm,
                          const float* __restrict__ cbn,
                          const float* __restrict__ pv, const int* __restrict__ pi,
                          float* __restrict__ dout,
                          float* __restrict__ loss,
                          _Float16* __restrict__ af16, int q) {
    int wave = threadIdx.x >> 6, lane = threadIdx.x & 63;
    int row = blockIdx.x * 4 + wave;
    float* xr = resid + (size_t)row * DD;
    float nrm = rnrm[row];
    float4 a0 = *(float4*)&xr[lane * 8];
    float4 a1 = *(float4*)&xr[lane * 8 + 4];
    float orig[8] = {a0.x,a0.y,a0.z,a0.w,a1.x,a1.y,a1.z,a1.w};
    float x[8];
#pragma unroll
    for (int j = 0; j < 8; ++j) x[j] = orig[j] / nrm;   // x_n per reference

    // merge 32 chunk top-4 partials (lane i < 32 loads chunk i)
    float V[4] = {-3e38f, -3e38f, -3e38f, -3e38f};
    int   I[4] = {0x7fffffff, 0x7fffffff, 0x7fffffff, 0x7fffffff};
    if (lane < NB) {
        size_t o = ((size_t)row * NB + lane) * 4;
#pragma unroll
        for (int j = 0; j < 4; ++j) { V[j] = pv[o + j]; I[j] = pi[o + j]; }
    }
#pragma unroll
    for (int m = 1; m < 32; m <<= 1) {
#pragma unroll
        for (int j = 0; j < 4; ++j) {
            float ov = __shfl_xor(V[j], m, 64);
            int oc = __shfl_xor(I[j], m, 64);
            top4add(ov, oc, V, I);
        }
    }
    int cand[4];
#pragma unroll
    for (int j = 0; j < 4; ++j) cand[j] = __shfl(I[j], 0, 64);

    // exact fp32 rescore of the 4 nominated candidates on the normalized row
    float sBest = -3e38f; int idx = 0x7fffffff;
#pragma unroll
    for (int j = 0; j < 4; ++j) {
        const float* cbj = cbn + (size_t)cand[j] * DD;
        float s = 0.f;
#pragma unroll
        for (int e = 0; e < 8; ++e) s += x[e] * cbj[lane * 8 + e];
        s = waveSum(s);
        if (s > sBest || (s == sBest && cand[j] < idx)) { sBest = s; idx = cand[j]; }
    }

    const float* qp = cbn + (size_t)idx * DD;
    float4 q0 = *(const float4*)&qp[lane * 8];
    float4 q1 = *(const float4*)&qp[lane * 8 + 4];
    float qv[8] = {q0.x,q0.y,q0.z,q0.w,q1.x,q1.y,q1.z,q1.w};

    float ns2 = 0.f, nt2 = 0.f, lrow = 0.f;
#pragma unroll
    for (int j = 0; j < 8; ++j) {
        ns2 += x[j] * x[j];
        nt2 += qv[j] * qv[j];
        float d = x[j] - qv[j];
        lrow += d * d;
    }
    ns2 = waveSum(ns2); nt2 = waveSum(nt2); lrow = waveSum(lrow);
    float ns = sqrtf(ns2), nt = sqrtf(nt2);

    float u[8], qn[8], wv[8];
    float nw2 = 0.f;
#pragma unroll
    for (int j = 0; j < 8; ++j) {
        u[j] = x[j] / ns;
        qn[j] = qv[j] / nt;
        wv[j] = u[j] + qn[j];
        nw2 += wv[j] * wv[j];
    }
    nw2 = waveSum(nw2);
    float nw = fmaxf(sqrtf(nw2), 1e-12f);
    float dew = 0.f, deu = 0.f;
#pragma unroll
    for (int j = 0; j < 8; ++j) {
        wv[j] = wv[j] / nw;
        dew += x[j] * wv[j];
        deu += x[j] * u[j];
    }
    dew = waveSum(dew); deu = waveSum(deu);
    float scale = nt / ns;

    float r[8], nres[8];
    float ss = 0.f;
#pragma unroll
    for (int j = 0; j < 8; ++j) {
        r[j] = (x[j] - 2.0f * dew * wv[j] + 2.0f * deu * qn[j]) * scale;
        nres[j] = orig[j] - r[j];
        ss += nres[j] * nres[j];
    }

    // residual -= r ; emit f16 residual + next rnrm (fused residCvt)
    *(float4*)&xr[lane * 8]     = make_float4(nres[0], nres[1], nres[2], nres[3]);
    *(float4*)&xr[lane * 8 + 4] = make_float4(nres[4], nres[5], nres[6], nres[7]);
    ss = waveSum(ss);
    if (lane == 0) rnrm[row] = fmaxf(sqrtf(ss), 1e-12f);
    f16x8 hv;
#pragma unroll
    for (int j = 0; j < 8; ++j) hv[j] = (_Float16)nres[j];
    *(f16x8*)&af16[(size_t)row * DD + lane * 8] = hv;

    float* op = dout + (size_t)row * DD;
    float4 o0 = *(float4*)&op[lane * 8];
    float4 o1 = *(float4*)&op[lane * 8 + 4];
    o0.x += r[0]; o0.y += r[1]; o0.z += r[2]; o0.w += r[3];
    o1.x += r[4]; o1.y += r[5]; o1.z += r[6]; o1.w += r[7];
    *(float4*)&op[lane * 8] = o0;
    *(float4*)&op[lane * 8 + 4] = o1;

    if (lane == 0) {
        dout[IDX_OFF + row * 4 + q] = (float)idx;
        atomicAdd(loss + q, lrow * LOSS_COEF);
    }
}

__global__ void lossWriteK(const float* __restrict__ loss, float* __restrict__ dout) {
    if (threadIdx.x < QQ) dout[LOSS_OFF + threadIdx.x] = loss[threadIdx.x];
}

extern "C" void kernel_launch(void* const* d_in, const int* in_sizes, int n_in,
                              void* d_out, int out_size, void* d_ws, size_t ws_size,
                              hipStream_t stream) {
    const float* x = (const float*)d_in[0];
    const float* codebooks = (const float*)d_in[1];
    const float* weights = (const float*)d_in[2];
    float* dout = (float*)d_out;
    float* w = (float*)d_ws;

    float* resid = w + WS_RESID;
    float* cbn   = w + WS_CBN;
    float* rnrm  = w + WS_RNRM;
    float* pv    = w + WS_PV;
    int*   pi    = (int*)(w + WS_PI);
    float* loss  = w + WS_LOSS;
    _Float16* f16base = (_Float16*)(w + WS_F16);
    _Float16* Af16 = f16base + F16_A;
    _Float16* Bf16 = f16base + F16_B;

    initK<<<4096, 256, 0, stream>>>(x, resid, dout, loss);
    residCvtK<<<RR / 4, 256, 0, stream>>>(resid, rnrm, Af16);

    for (int q = 0; q < QQ; ++q) {
        gemmCbK<<<dim3(CC / 64, DD / 64), 256, 0, stream>>>(
            codebooks + (size_t)q * CC * DD, weights + (size_t)q * DD * DD, cbn);
        rowNormCvtK<<<CC / 4, 256, 0, stream>>>(cbn, Bf16);
        simMfmaK<<<dim3(RR / 128, NB), 512, 0, stream>>>(Af16, Bf16, pv, pi);
        finalizeK<<<RR / 4, 256, 0, stream>>>(resid, rnrm, cbn, pv, pi,
                                              dout, loss, Af16, q);
    }
    lossWriteK<<<1, 64, 0, stream>>>(loss, dout);
}